// Round 11
// baseline (363.405 us; speedup 1.0000x reference)
//
#include <hip/hip_runtime.h>
#include <stdint.h>

#define HASH_BUCKETS 1000
#define EMB_DIM 16
#define HDIM 32
#define G4 128   // 4*HDIM
#define TSTEPS 512
#define BATCH 4096

typedef short v8s __attribute__((ext_vector_type(8)));   // 8 bf16 (4 VGPRs)
typedef float v4f __attribute__((ext_vector_type(4)));   // MFMA acc

__device__ __forceinline__ float frcp(float x) {
    float r; asm("v_rcp_f32 %0, %1" : "=v"(r) : "v"(x)); return r;
}
__device__ __forceinline__ float fexp2(float x) {
    float r; asm("v_exp_f32 %0, %1" : "=v"(r) : "v"(x)); return r;
}
// f32 -> bf16 (RNE), bits in low 16
__device__ __forceinline__ uint32_t bf16rne(float x) {
    uint32_t u = __float_as_uint(x);
    return (u + 0x7FFFu + ((u >> 16) & 1u)) >> 16;
}

// ---------------------------------------------------------------------------
// Kernel 1: fold embedding through input projection:
// P2[bucket][h][g] = sum_e emb[bucket][e] * kernel[e][g*32 + h]
// ---------------------------------------------------------------------------
__global__ void precompute_P2_kernel(const float* __restrict__ emb,
                                     const float* __restrict__ kern,
                                     float* __restrict__ P2) {
    int idx = blockIdx.x * blockDim.x + threadIdx.x;
    if (idx >= HASH_BUCKETS * G4) return;
    int row = idx >> 7;
    int c2  = idx & 127;
    int h = c2 >> 2;
    int g = c2 & 3;
    float acc = 0.f;
#pragma unroll
    for (int e = 0; e < EMB_DIM; ++e)
        acc = fmaf(emb[row * EMB_DIM + e], kern[e * G4 + g * 32 + h], acc);
    P2[idx] = acc;
}

// ---------------------------------------------------------------------------
// Kernel 2: MFMA LSTM, stall-minimized structure.
// Block = 256 threads = 4 waves = 16 batch (grid 256, 1 wave/SIMD, 1 blk/CU).
// Wave w computes z^T row-chunks 2w and 2w+1 (16x16x32 bf16 MFMA, split-bf16
// x3 with 3 INDEPENDENT acc chains), rows permuted so lane (quad,col) gets
// (i,f,c,o) of (h_idx = 8w+quad, batch=col) and (h_idx = 8w+4+quad, batch=col)
// -> 2 gate chains per lane (ILP-2 over the serial chain latency).
// One __syncthreads per step couples only 4 waves; 12 DS ops/CU-step.
// Gates: per-gate independent rcp (no serial product tree), exp2-based,
// args clamped <=31.
// ---------------------------------------------------------------------------
__global__ __launch_bounds__(256)
__attribute__((amdgpu_waves_per_eu(1, 1)))
void lstm_head_kernel(const int* __restrict__ ids,
                      const float* __restrict__ P2,   // [1000][32][4]
                      const float* __restrict__ R,    // rec_kernel [32][128]
                      const float* __restrict__ w1,   // [32][32]
                      const float* __restrict__ b1,   // [32]
                      const float* __restrict__ w2,   // [32]
                      const float* __restrict__ b2,   // [1]
                      float* __restrict__ out) {
    // packed h: dword = (hi_bf16 << 16) | lo_bf16; stride 36 dwords -> 2-way
    // max bank aliasing on both write (4col+h) and b128 read patterns.
    __shared__ __align__(16) uint32_t hbuf[2][16][36];
    __shared__ float hfin[16][33];

    const int tid  = threadIdx.x;
    const int w    = tid >> 6;        // wave 0..3
    const int lane = tid & 63;
    const int col  = lane & 15;       // batch within group / A row m / B col n
    const int quad = lane >> 4;       // 0..3
    const int bb   = blockIdx.x * 16;
    const int h0   = 8 * w + quad;    // chain-0 h index
    const int h1   = h0 + 4;          // chain-1 h index

    // ---- A fragments for chunks 2w (gc0) and 2w+1 (gc1) ----
    union V8 { uint32_t u[4]; v8s v; };
    V8 A0hi, A0lo, A1hi, A1lo;
    {
        int tt = col >> 2, g = col & 3;
        int gc0 = g * 32 + 8 * w + tt;      // chunk 2w
        int gc1 = gc0 + 4;                  // chunk 2w+1
#pragma unroll
        for (int r = 0; r < 4; ++r) {
            uint32_t h0p[2], l0p[2], h1p[2], l1p[2];
#pragma unroll
            for (int e = 0; e < 2; ++e) {
                int k = quad * 8 + 2 * r + e;
                float x0 = R[k * G4 + gc0];
                uint32_t hb0 = bf16rne(x0);
                h0p[e] = hb0;
                l0p[e] = bf16rne(x0 - __uint_as_float(hb0 << 16));
                float x1 = R[k * G4 + gc1];
                uint32_t hb1 = bf16rne(x1);
                h1p[e] = hb1;
                l1p[e] = bf16rne(x1 - __uint_as_float(hb1 << 16));
            }
            A0hi.u[r] = h0p[0] | (h0p[1] << 16);
            A0lo.u[r] = l0p[0] | (l0p[1] << 16);
            A1hi.u[r] = h1p[0] | (h1p[1] << 16);
            A1lo.u[r] = l1p[0] | (l1p[1] << 16);
        }
    }

    // zero read buffer (h0 = 0); write buffer is fully overwritten each step
    for (int i = tid; i < 2 * 16 * 36; i += 256)
        ((uint32_t*)hbuf)[i] = 0u;

    // ---- id / xz pipeline (per lane: batch = col) ----
    const int* __restrict__ idrow = ids + (size_t)(bb + col) * TSTEPS;
    int idn = idrow[0];
    float4 xz0 = *(const float4*)(P2 + (size_t)idn * G4 + 4 * h0);
    float4 xz1 = *(const float4*)(P2 + (size_t)idn * G4 + 4 * h1);
    idn = idrow[1];

    float c0 = 0.f, c1 = 0.f, hv0 = 0.f, hv1 = 0.f;
    int p = 0;
    const float NL2E = -1.4426950408889634f;
    const float PL2E =  2.8853900817779268f;
    const v4f vzero = {0.f, 0.f, 0.f, 0.f};

    __syncthreads();

    for (int t = 0; t < TSTEPS; ++t) {
        // B fragment source: 8 packed dwords (k = quad*8 + e), batch = col
        const uint32_t* hrow = &hbuf[p][col][0] + 8 * quad;
        uint4 dA = *(const uint4*)hrow;
        uint4 dB = *(const uint4*)(hrow + 4);

        // prefetch next xz (both chains) / next-next id while reads land
        float4 xzn0 = *(const float4*)(P2 + (size_t)idn * G4 + 4 * h0);
        float4 xzn1 = *(const float4*)(P2 + (size_t)idn * G4 + 4 * h1);
        int idnn = idrow[(t + 2 < TSTEPS) ? (t + 2) : (TSTEPS - 1)];

        V8 Bhi, Blo;
        Bhi.u[0] = __builtin_amdgcn_perm(dA.y, dA.x, 0x07060302u);
        Bhi.u[1] = __builtin_amdgcn_perm(dA.w, dA.z, 0x07060302u);
        Bhi.u[2] = __builtin_amdgcn_perm(dB.y, dB.x, 0x07060302u);
        Bhi.u[3] = __builtin_amdgcn_perm(dB.w, dB.z, 0x07060302u);
        Blo.u[0] = __builtin_amdgcn_perm(dA.y, dA.x, 0x05040100u);
        Blo.u[1] = __builtin_amdgcn_perm(dA.w, dA.z, 0x05040100u);
        Blo.u[2] = __builtin_amdgcn_perm(dB.y, dB.x, 0x05040100u);
        Blo.u[3] = __builtin_amdgcn_perm(dB.w, dB.z, 0x05040100u);

        // z = Ahi*Bhi + Ahi*Blo + Alo*Bhi + xz  (lo*lo dropped)
        // 3 acc chains, chunks interleaved -> MFMA latency hidden
        v4f s0a = __builtin_amdgcn_mfma_f32_16x16x32_bf16(A0lo.v, Bhi.v, vzero, 0, 0, 0);
        v4f s1a = __builtin_amdgcn_mfma_f32_16x16x32_bf16(A1lo.v, Bhi.v, vzero, 0, 0, 0);
        v4f s0b = __builtin_amdgcn_mfma_f32_16x16x32_bf16(A0hi.v, Blo.v, s0a, 0, 0, 0);
        v4f s1b = __builtin_amdgcn_mfma_f32_16x16x32_bf16(A1hi.v, Blo.v, s1a, 0, 0, 0);
        v4f xzv0 = {xz0.x, xz0.y, xz0.z, xz0.w};
        v4f xzv1 = {xz1.x, xz1.y, xz1.z, xz1.w};
        v4f s0c = __builtin_amdgcn_mfma_f32_16x16x32_bf16(A0hi.v, Bhi.v, xzv0, 0, 0, 0);
        v4f s1c = __builtin_amdgcn_mfma_f32_16x16x32_bf16(A1hi.v, Bhi.v, xzv1, 0, 0, 0);
        v4f z0 = s0c + s0b;
        v4f z1 = s1c + s1b;

        // ---- gate chains (2 per lane, max ILP: per-gate independent rcp) ----
        float si0 = frcp(1.f + fexp2(fminf(31.f, NL2E * z0[0])));
        float sf0 = frcp(1.f + fexp2(fminf(31.f, NL2E * z0[1])));
        float tz0 = fmaf(-2.f, frcp(1.f + fexp2(fminf(31.f, PL2E * z0[2]))), 1.f);
        float so0 = frcp(1.f + fexp2(fminf(31.f, NL2E * z0[3])));
        float si1 = frcp(1.f + fexp2(fminf(31.f, NL2E * z1[0])));
        float sf1 = frcp(1.f + fexp2(fminf(31.f, NL2E * z1[1])));
        float tz1 = fmaf(-2.f, frcp(1.f + fexp2(fminf(31.f, PL2E * z1[2]))), 1.f);
        float so1 = frcp(1.f + fexp2(fminf(31.f, NL2E * z1[3])));

        c0 = fmaf(sf0, c0, si0 * tz0);
        c1 = fmaf(sf1, c1, si1 * tz1);
        float tc0 = fmaf(-2.f, frcp(1.f + fexp2(fminf(31.f, PL2E * c0))), 1.f);
        float tc1 = fmaf(-2.f, frcp(1.f + fexp2(fminf(31.f, PL2E * c1))), 1.f);
        hv0 = so0 * tc0;
        hv1 = so1 * tc1;

        // publish h (split-bf16 packed) for next step
        uint32_t hb0 = bf16rne(hv0);
        uint32_t pk0 = (hb0 << 16) | bf16rne(hv0 - __uint_as_float(hb0 << 16));
        uint32_t hb1 = bf16rne(hv1);
        uint32_t pk1 = (hb1 << 16) | bf16rne(hv1 - __uint_as_float(hb1 << 16));
        hbuf[p ^ 1][col][h0] = pk0;
        hbuf[p ^ 1][col][h1] = pk1;

        xz0 = xzn0;
        xz1 = xzn1;
        idn = idnn;
        __syncthreads();
        p ^= 1;
    }

    // ---- MLP head ----
    hfin[col][h0] = hv0;
    hfin[col][h1] = hv1;
    __syncthreads();

    int u = tid & 31;
    for (int bq = tid >> 5; bq < 16; bq += 8) {
        float y = b1[u];
#pragma unroll
        for (int k = 0; k < HDIM; ++k)
            y = fmaf(hfin[bq][k], w1[k * HDIM + u], y);
        y = fmaxf(y, 0.f);
        float vv = y * w2[u];
#pragma unroll
        for (int off = 16; off >= 1; off >>= 1)
            vv += __shfl_xor(vv, off);   // stays within each 32-lane group
        if (u == 0) out[bb + bq] = vv + b2[0];
    }
}

extern "C" void kernel_launch(void* const* d_in, const int* in_sizes, int n_in,
                              void* d_out, int out_size, void* d_ws, size_t ws_size,
                              hipStream_t stream) {
    const int*   ids  = (const int*)d_in[0];
    const float* emb  = (const float*)d_in[1];
    const float* kern = (const float*)d_in[2];
    const float* rec  = (const float*)d_in[3];
    const float* w1   = (const float*)d_in[4];
    const float* b1   = (const float*)d_in[5];
    const float* w2   = (const float*)d_in[6];
    const float* b2   = (const float*)d_in[7];
    float* out = (float*)d_out;
    float* P2  = (float*)d_ws;   // 512 KB scratch

    precompute_P2_kernel<<<(HASH_BUCKETS * G4 + 255) / 256, 256, 0, stream>>>(
        emb, kern, P2);
    lstm_head_kernel<<<BATCH / 16, 256, 0, stream>>>(
        ids, P2, rec, w1, b1, w2, b2, out);
}

// Round 12
// 323.223 us; speedup vs baseline: 1.1243x; 1.1243x over previous
//
#include <hip/hip_runtime.h>
#include <stdint.h>

#define HASH_BUCKETS 1000
#define EMB_DIM 16
#define HDIM 32
#define G4 128   // 4*HDIM
#define TSTEPS 512
#define BATCH 4096

typedef short v8s __attribute__((ext_vector_type(8)));   // 8 bf16 (4 VGPRs)
typedef float v4f __attribute__((ext_vector_type(4)));   // MFMA acc

__device__ __forceinline__ float frcp(float x) {
    float r; asm("v_rcp_f32 %0, %1" : "=v"(r) : "v"(x)); return r;
}
__device__ __forceinline__ float fexp2(float x) {
    float r; asm("v_exp_f32 %0, %1" : "=v"(r) : "v"(x)); return r;
}
// f32 -> bf16 (RNE), bits in low 16
__device__ __forceinline__ uint32_t bf16rne(float x) {
    uint32_t u = __float_as_uint(x);
    return (u + 0x7FFFu + ((u >> 16) & 1u)) >> 16;
}

// ---------------------------------------------------------------------------
// Kernel 1: fold embedding through input projection:
// P2[bucket][h][g] = sum_e emb[bucket][e] * kernel[e][g*32 + h]
// ---------------------------------------------------------------------------
__global__ void precompute_P2_kernel(const float* __restrict__ emb,
                                     const float* __restrict__ kern,
                                     float* __restrict__ P2) {
    int idx = blockIdx.x * blockDim.x + threadIdx.x;
    if (idx >= HASH_BUCKETS * G4) return;
    int row = idx >> 7;
    int c2  = idx & 127;
    int h = c2 >> 2;
    int g = c2 & 3;
    float acc = 0.f;
#pragma unroll
    for (int e = 0; e < EMB_DIM; ++e)
        acc = fmaf(emb[row * EMB_DIM + e], kern[e * G4 + g * 32 + h], acc);
    P2[idx] = acc;
}

// ---------------------------------------------------------------------------
// Kernel 2: MFMA LSTM. Identical to round 11 EXCEPT the global prefetch
// pipeline is deepened: xz loads are issued 2 steps ahead (ids 4 ahead), so
// at the compiler's mandatory `s_waitcnt vmcnt(0)` before each s_barrier the
// outstanding loads are already ~1 loop body (>=800 cyc) old and the drain is
// free. (Round 8-11 all issued loads ~immediately before the drain -> every
// step serially paid ~250-400 cyc of L2 gather latency; this was the
// invariant wall across all three structures.)
// ---------------------------------------------------------------------------
__global__ __launch_bounds__(256)
__attribute__((amdgpu_waves_per_eu(1, 1)))
void lstm_head_kernel(const int* __restrict__ ids,
                      const float* __restrict__ P2,   // [1000][32][4]
                      const float* __restrict__ R,    // rec_kernel [32][128]
                      const float* __restrict__ w1,   // [32][32]
                      const float* __restrict__ b1,   // [32]
                      const float* __restrict__ w2,   // [32]
                      const float* __restrict__ b2,   // [1]
                      float* __restrict__ out) {
    __shared__ __align__(16) uint32_t hbuf[2][16][36];
    __shared__ float hfin[16][33];

    const int tid  = threadIdx.x;
    const int w    = tid >> 6;        // wave 0..3
    const int lane = tid & 63;
    const int col  = lane & 15;       // batch within group
    const int quad = lane >> 4;       // 0..3
    const int bb   = blockIdx.x * 16;
    const int h0   = 8 * w + quad;
    const int h1   = h0 + 4;

    // ---- A fragments for chunks 2w (gc0) and 2w+1 (gc1) ----
    union V8 { uint32_t u[4]; v8s v; };
    V8 A0hi, A0lo, A1hi, A1lo;
    {
        int tt = col >> 2, g = col & 3;
        int gc0 = g * 32 + 8 * w + tt;
        int gc1 = gc0 + 4;
#pragma unroll
        for (int r = 0; r < 4; ++r) {
            uint32_t h0p[2], l0p[2], h1p[2], l1p[2];
#pragma unroll
            for (int e = 0; e < 2; ++e) {
                int k = quad * 8 + 2 * r + e;
                float x0 = R[k * G4 + gc0];
                uint32_t hb0 = bf16rne(x0);
                h0p[e] = hb0;
                l0p[e] = bf16rne(x0 - __uint_as_float(hb0 << 16));
                float x1 = R[k * G4 + gc1];
                uint32_t hb1 = bf16rne(x1);
                h1p[e] = hb1;
                l1p[e] = bf16rne(x1 - __uint_as_float(hb1 << 16));
            }
            A0hi.u[r] = h0p[0] | (h0p[1] << 16);
            A0lo.u[r] = l0p[0] | (l0p[1] << 16);
            A1hi.u[r] = h1p[0] | (h1p[1] << 16);
            A1lo.u[r] = l1p[0] | (l1p[1] << 16);
        }
    }

    for (int i = tid; i < 2 * 16 * 36; i += 256)
        ((uint32_t*)hbuf)[i] = 0u;

    // ---- deep prefetch pipeline ----
    // xz_c = xz[t] (ready), xz_n = xz[t+1] (ready), xz_f = xz[t+2] (in flight,
    // issued at top of iter t). id_c = id[t+2] (ready), id_n = id[t+3].
    const int* __restrict__ idrow = ids + (size_t)(bb + col) * TSTEPS;
    int ida = idrow[0];
    float4 xz0_c = *(const float4*)(P2 + (size_t)ida * G4 + 4 * h0);
    float4 xz1_c = *(const float4*)(P2 + (size_t)ida * G4 + 4 * h1);
    int idb = idrow[1];
    float4 xz0_n = *(const float4*)(P2 + (size_t)idb * G4 + 4 * h0);
    float4 xz1_n = *(const float4*)(P2 + (size_t)idb * G4 + 4 * h1);
    int id_c = idrow[2];
    int id_n = idrow[3];

    float c0 = 0.f, c1 = 0.f, hv0 = 0.f, hv1 = 0.f;
    int p = 0;
    const float NL2E = -1.4426950408889634f;
    const float PL2E =  2.8853900817779268f;
    const v4f vzero = {0.f, 0.f, 0.f, 0.f};

    __syncthreads();

    for (int t = 0; t < TSTEPS; ++t) {
        // issue xz[t+2] NOW (consumed 2 iterations later; at this step's
        // barrier drain these are the only fresh vmem ops, aged ~full body
        // by then -> drain ~free)
        float4 xz0_f = *(const float4*)(P2 + (size_t)id_c * G4 + 4 * h0);
        float4 xz1_f = *(const float4*)(P2 + (size_t)id_c * G4 + 4 * h1);
        int id_f = idrow[(t + 4 < TSTEPS) ? (t + 4) : (TSTEPS - 1)];

        // B fragment: 8 packed dwords (k = quad*8 + e), batch = col
        const uint32_t* hrow = &hbuf[p][col][0] + 8 * quad;
        uint4 dA = *(const uint4*)hrow;
        uint4 dB = *(const uint4*)(hrow + 4);

        V8 Bhi, Blo;
        Bhi.u[0] = __builtin_amdgcn_perm(dA.y, dA.x, 0x07060302u);
        Bhi.u[1] = __builtin_amdgcn_perm(dA.w, dA.z, 0x07060302u);
        Bhi.u[2] = __builtin_amdgcn_perm(dB.y, dB.x, 0x07060302u);
        Bhi.u[3] = __builtin_amdgcn_perm(dB.w, dB.z, 0x07060302u);
        Blo.u[0] = __builtin_amdgcn_perm(dA.y, dA.x, 0x05040100u);
        Blo.u[1] = __builtin_amdgcn_perm(dA.w, dA.z, 0x05040100u);
        Blo.u[2] = __builtin_amdgcn_perm(dB.y, dB.x, 0x05040100u);
        Blo.u[3] = __builtin_amdgcn_perm(dB.w, dB.z, 0x05040100u);

        // z = Ahi*Bhi + Ahi*Blo + Alo*Bhi + xz  (lo*lo dropped)
        v4f s0a = __builtin_amdgcn_mfma_f32_16x16x32_bf16(A0lo.v, Bhi.v, vzero, 0, 0, 0);
        v4f s1a = __builtin_amdgcn_mfma_f32_16x16x32_bf16(A1lo.v, Bhi.v, vzero, 0, 0, 0);
        v4f s0b = __builtin_amdgcn_mfma_f32_16x16x32_bf16(A0hi.v, Blo.v, s0a, 0, 0, 0);
        v4f s1b = __builtin_amdgcn_mfma_f32_16x16x32_bf16(A1hi.v, Blo.v, s1a, 0, 0, 0);
        v4f xzv0 = {xz0_c.x, xz0_c.y, xz0_c.z, xz0_c.w};
        v4f xzv1 = {xz1_c.x, xz1_c.y, xz1_c.z, xz1_c.w};
        v4f s0c = __builtin_amdgcn_mfma_f32_16x16x32_bf16(A0hi.v, Bhi.v, xzv0, 0, 0, 0);
        v4f s1c = __builtin_amdgcn_mfma_f32_16x16x32_bf16(A1hi.v, Bhi.v, xzv1, 0, 0, 0);
        v4f z0 = s0c + s0b;
        v4f z1 = s1c + s1b;

        // ---- gate chains (2 per lane) ----
        float si0 = frcp(1.f + fexp2(fminf(31.f, NL2E * z0[0])));
        float sf0 = frcp(1.f + fexp2(fminf(31.f, NL2E * z0[1])));
        float tz0 = fmaf(-2.f, frcp(1.f + fexp2(fminf(31.f, PL2E * z0[2]))), 1.f);
        float so0 = frcp(1.f + fexp2(fminf(31.f, NL2E * z0[3])));
        float si1 = frcp(1.f + fexp2(fminf(31.f, NL2E * z1[0])));
        float sf1 = frcp(1.f + fexp2(fminf(31.f, NL2E * z1[1])));
        float tz1 = fmaf(-2.f, frcp(1.f + fexp2(fminf(31.f, PL2E * z1[2]))), 1.f);
        float so1 = frcp(1.f + fexp2(fminf(31.f, NL2E * z1[3])));

        c0 = fmaf(sf0, c0, si0 * tz0);
        c1 = fmaf(sf1, c1, si1 * tz1);
        float tc0 = fmaf(-2.f, frcp(1.f + fexp2(fminf(31.f, PL2E * c0))), 1.f);
        float tc1 = fmaf(-2.f, frcp(1.f + fexp2(fminf(31.f, PL2E * c1))), 1.f);
        hv0 = so0 * tc0;
        hv1 = so1 * tc1;

        // publish h (split-bf16 packed)
        uint32_t hb0 = bf16rne(hv0);
        uint32_t pk0 = (hb0 << 16) | bf16rne(hv0 - __uint_as_float(hb0 << 16));
        uint32_t hb1 = bf16rne(hv1);
        uint32_t pk1 = (hb1 << 16) | bf16rne(hv1 - __uint_as_float(hb1 << 16));
        hbuf[p ^ 1][col][h0] = pk0;
        hbuf[p ^ 1][col][h1] = pk1;

        // rotate pipelines
        xz0_c = xz0_n; xz1_c = xz1_n;
        xz0_n = xz0_f; xz1_n = xz1_f;
        id_c = id_n;
        id_n = id_f;

        __syncthreads();
        p ^= 1;
    }

    // ---- MLP head ----
    hfin[col][h0] = hv0;
    hfin[col][h1] = hv1;
    __syncthreads();

    int u = tid & 31;
    for (int bq = tid >> 5; bq < 16; bq += 8) {
        float y = b1[u];
#pragma unroll
        for (int k = 0; k < HDIM; ++k)
            y = fmaf(hfin[bq][k], w1[k * HDIM + u], y);
        y = fmaxf(y, 0.f);
        float vv = y * w2[u];
#pragma unroll
        for (int off = 16; off >= 1; off >>= 1)
            vv += __shfl_xor(vv, off);
        if (u == 0) out[bb + bq] = vv + b2[0];
    }
}

extern "C" void kernel_launch(void* const* d_in, const int* in_sizes, int n_in,
                              void* d_out, int out_size, void* d_ws, size_t ws_size,
                              hipStream_t stream) {
    const int*   ids  = (const int*)d_in[0];
    const float* emb  = (const float*)d_in[1];
    const float* kern = (const float*)d_in[2];
    const float* rec  = (const float*)d_in[3];
    const float* w1   = (const float*)d_in[4];
    const float* b1   = (const float*)d_in[5];
    const float* w2   = (const float*)d_in[6];
    const float* b2   = (const float*)d_in[7];
    float* out = (float*)d_out;
    float* P2  = (float*)d_ws;   // 512 KB scratch

    precompute_P2_kernel<<<(HASH_BUCKETS * G4 + 255) / 256, 256, 0, stream>>>(
        emb, kern, P2);
    lstm_head_kernel<<<BATCH / 16, 256, 0, stream>>>(
        ids, P2, rec, w1, b1, w2, b2, out);
}